// Round 9
// baseline (75.559 us; speedup 1.0000x reference)
//
#include <hip/hip_runtime.h>

#define LOG2E 1.4426950408889634f
#define TWO_LOG2E 2.885390081777927f

__device__ __forceinline__ float fast_exp2(float x) { return __builtin_amdgcn_exp2f(x); }
__device__ __forceinline__ float fast_rcp(float x)  { return __builtin_amdgcn_rcpf(x); }

// ---------------------------------------------------------------------------
// K1: projections + exp transform. Virtual M=4096 rows: blocks 0..255 ->
// exp2(2*log2e * query*Wq) -> eq, blocks 256..511 -> value*Wv -> ek.
// 8 rows per block, 256 threads (one output column each).
// ---------------------------------------------------------------------------
__global__ __launch_bounds__(256) void proj_kernel(
    const float* __restrict__ query, const float* __restrict__ value,
    const float* __restrict__ Wq, const float* __restrict__ Wv,
    float* __restrict__ eq, float* __restrict__ ek)
{
    __shared__ float in_lds[8 * 256];
    const int t = threadIdx.x;
    const int row0 = blockIdx.x * 8;
    const float* src; const float* W; float* dst;
    if (row0 < 2048) { src = query + (size_t)row0 * 256; W = Wq; dst = eq + (size_t)row0 * 256; }
    else { const int r = row0 - 2048; src = value + (size_t)r * 256; W = Wv; dst = ek + (size_t)r * 256; }

    const float4* s4 = (const float4*)src;
    float4* l4 = (float4*)in_lds;
    l4[t] = s4[t];
    l4[t + 256] = s4[t + 256];
    __syncthreads();

    float acc[8];
#pragma unroll
    for (int r = 0; r < 8; ++r) acc[r] = 0.f;

    for (int d = 0; d < 256; d += 4) {
        const float w0 = W[(d + 0) * 256 + t];
        const float w1 = W[(d + 1) * 256 + t];
        const float w2 = W[(d + 2) * 256 + t];
        const float w3 = W[(d + 3) * 256 + t];
#pragma unroll
        for (int r = 0; r < 8; ++r) {
            const float4 v = *(const float4*)&in_lds[r * 256 + d];
            acc[r] = fmaf(v.x, w0, acc[r]);
            acc[r] = fmaf(v.y, w1, acc[r]);
            acc[r] = fmaf(v.z, w2, acc[r]);
            acc[r] = fmaf(v.w, w3, acc[r]);
        }
    }
#pragma unroll
    for (int r = 0; r < 8; ++r) dst[r * 256 + t] = fast_exp2(acc[r] * TWO_LOG2E);
}

// ---------------------------------------------------------------------------
// K2: shifted additive scores, d-split x2, paired-rcp body (unchanged R7).
// ---------------------------------------------------------------------------
#define SQ_ST 130
__global__ __launch_bounds__(256) void scores_kernel(
    const float* __restrict__ eq, const float* __restrict__ ek,
    const float* __restrict__ scale,
    float* __restrict__ part0, float* __restrict__ part1)
{
    __shared__ float q_lds[32 * SQ_ST];
    __shared__ float k_lds[32 * SQ_ST];
    __shared__ float sc_lds[128];

    const int t = threadIdx.x;
    const int tx = t & 15, ty = t >> 4;
    const int kt = blockIdx.x, qt = blockIdx.y;
    const int b = blockIdx.z >> 1, dh = blockIdx.z & 1;
    const int d0 = dh * 128;
    const float* qbase = eq + (size_t)(b * 512 + qt * 32) * 256 + d0;
    const float* kbase = ek + (size_t)(b * 512 + kt * 32) * 256 + d0;

    if (t < 128) sc_lds[t] = -2.f * scale[d0 + t];

#pragma unroll
    for (int l = 0; l < 4; ++l) {
        const int idx = t + 256 * l;
        const int row = idx >> 5, c4 = (idx & 31) * 4;
        const float4 qv = *(const float4*)&qbase[row * 256 + c4];
        const float4 kv = *(const float4*)&kbase[row * 256 + c4];
        *(float2*)&q_lds[row * SQ_ST + c4]     = make_float2(qv.x, qv.y);
        *(float2*)&q_lds[row * SQ_ST + c4 + 2] = make_float2(qv.z, qv.w);
        *(float2*)&k_lds[row * SQ_ST + c4]     = make_float2(kv.x, kv.y);
        *(float2*)&k_lds[row * SQ_ST + c4 + 2] = make_float2(kv.z, kv.w);
    }
    __syncthreads();

    float a00 = 0.f, a01 = 0.f, a10 = 0.f, a11 = 0.f;

#pragma unroll 4
    for (int d = 0; d < 128; d += 2) {
        const float2 s2 = *(const float2*)&sc_lds[d];
        const float2 qa = *(const float2*)&q_lds[(ty * 2 + 0) * SQ_ST + d];
        const float2 qb = *(const float2*)&q_lds[(ty * 2 + 1) * SQ_ST + d];
        const float2 ka = *(const float2*)&k_lds[(tx * 2 + 0) * SQ_ST + d];
        const float2 kb = *(const float2*)&k_lds[(tx * 2 + 1) * SQ_ST + d];

        {
            const float A = fmaf(qa.x, ka.x, 1.f), B = fmaf(qa.y, ka.y, 1.f);
            a00 = fmaf(fmaf(s2.y, A, s2.x * B), fast_rcp(A * B), a00);
        }
        {
            const float A = fmaf(qa.x, kb.x, 1.f), B = fmaf(qa.y, kb.y, 1.f);
            a01 = fmaf(fmaf(s2.y, A, s2.x * B), fast_rcp(A * B), a01);
        }
        {
            const float A = fmaf(qb.x, ka.x, 1.f), B = fmaf(qb.y, ka.y, 1.f);
            a10 = fmaf(fmaf(s2.y, A, s2.x * B), fast_rcp(A * B), a10);
        }
        {
            const float A = fmaf(qb.x, kb.x, 1.f), B = fmaf(qb.y, kb.y, 1.f);
            a11 = fmaf(fmaf(s2.y, A, s2.x * B), fast_rcp(A * B), a11);
        }
    }

    float* part = dh ? part1 : part0;
    const int qrow = qt * 32 + ty * 2;
    const int kcol = kt * 32 + tx * 2;
    *(float2*)&part[(size_t)(b * 512 + qrow + 0) * 512 + kcol] = make_float2(a00, a01);
    *(float2*)&part[(size_t)(b * 512 + qrow + 1) * 512 + kcol] = make_float2(a10, a11);
}

// ---------------------------------------------------------------------------
// K3: FUSED softmax + PV. Block = (b, 8 q-rows), 512 threads (8 waves),
// grid 64x4 = 256 blocks = exactly 1/CU (no tail).
// Phase 1: sum part0+part1 -> s_tile (8 x 512, stride 516).
// Phase 2: wave w = row w softmax: 8 elems/lane stride-64 (conflict-free
//          b32), shfl_xor reduce, write attn output, keep raw exp in LDS,
//          inv -> inv_lds.
// Phase 3: PV with value chunks (64 x 256 = 64KB LDS). Wave w owns cols
//          32w..32w+31; lane: row r = lane>>3, cols 32w+(lane&7)*4 (float4).
//          Per k per wave: 1 v-b128 (128B unique, 8-way broadcast) +
//          1 s-b32 (8 addrs, broadcast) + 4 fma/lane -> fma-bound, and the
//          value row is read once per block per k (8x less LDS traffic than
//          per-wave-all-cols).
// ---------------------------------------------------------------------------
#define ST_ROW 516
__global__ __launch_bounds__(512) void softpv_kernel(
    const float* __restrict__ part0, const float* __restrict__ part1,
    const float* __restrict__ value,
    float* __restrict__ attn, float* __restrict__ out)
{
    __shared__ float s_tile[8 * ST_ROW];
    __shared__ float v_lds[64 * 256];
    __shared__ float inv_lds[8];

    const int t = threadIdx.x;
    const int qt = blockIdx.x, b = blockIdx.y;
    const int q0 = qt * 8;
    const size_t rowbase = (size_t)(b * 512 + q0) * 512;

    // ---- Phase 1: sum partials into s_tile ----
    {
        const float4* p0 = (const float4*)(part0 + rowbase);
        const float4* p1 = (const float4*)(part1 + rowbase);
#pragma unroll
        for (int l = 0; l < 2; ++l) {
            const int idx = t + 512 * l;            // 0..1023 float4s of 8x512
            const int row = idx >> 7, c4 = idx & 127;
            float4 a = p0[idx];
            const float4 c = p1[idx];
            a.x += c.x; a.y += c.y; a.z += c.z; a.w += c.w;
            *(float4*)&s_tile[row * ST_ROW + c4 * 4] = a;
        }
    }
    __syncthreads();

    // ---- Phase 2: per-row softmax (wave w == row w) ----
    const int w = t >> 6, lane = t & 63;
    {
        float e[8];
        float m = -1e30f;
#pragma unroll
        for (int j = 0; j < 8; ++j) {
            e[j] = s_tile[w * ST_ROW + lane + 64 * j];
            m = fmaxf(m, e[j]);
        }
#pragma unroll
        for (int off = 32; off; off >>= 1) m = fmaxf(m, __shfl_xor(m, off));

        float sum = 0.f;
#pragma unroll
        for (int j = 0; j < 8; ++j) {
            e[j] = fast_exp2((e[j] - m) * LOG2E);
            sum += e[j];
        }
#pragma unroll
        for (int off = 32; off; off >>= 1) sum += __shfl_xor(sum, off);

        const float inv = fast_rcp(sum);
        float* arow = attn + rowbase + (size_t)w * 512;
#pragma unroll
        for (int j = 0; j < 8; ++j) {
            s_tile[w * ST_ROW + lane + 64 * j] = e[j];   // raw exp for PV
            arow[lane + 64 * j] = e[j] * inv;            // attn output
        }
        if (lane == 0) inv_lds[w] = inv;
    }

    // ---- Phase 3: PV ----
    const int r = lane >> 3;                 // output row 0..7
    const int c = 32 * w + (lane & 7) * 4;   // output cols c..c+3
    float4 acc = {0.f, 0.f, 0.f, 0.f};

    for (int kc = 0; kc < 512; kc += 64) {
        __syncthreads();                     // also orders Phase-2 writes
        const float4* vsrc = (const float4*)(value + (size_t)(b * 512 + kc) * 256);
#pragma unroll
        for (int l = 0; l < 8; ++l) {
            const int idx = t + 512 * l;     // 0..4095 float4s of 64x256
            *(float4*)&v_lds[idx * 4] = vsrc[idx];
        }
        __syncthreads();

#pragma unroll 4
        for (int k = 0; k < 64; ++k) {
            const float s = s_tile[r * ST_ROW + kc + k];
            const float4 v = *(const float4*)&v_lds[k * 256 + c];
            acc.x = fmaf(s, v.x, acc.x);
            acc.y = fmaf(s, v.y, acc.y);
            acc.z = fmaf(s, v.z, acc.z);
            acc.w = fmaf(s, v.w, acc.w);
        }
    }

    const float inv = inv_lds[r];
    acc.x *= inv; acc.y *= inv; acc.z *= inv; acc.w *= inv;
    *(float4*)&out[(size_t)(b * 512 + q0 + r) * 256 + c] = acc;
}

extern "C" void kernel_launch(void* const* d_in, const int* in_sizes, int n_in,
                              void* d_out, int out_size, void* d_ws, size_t ws_size,
                              hipStream_t stream) {
    const float* query = (const float*)d_in[0];
    const float* value = (const float*)d_in[1];
    const float* Wq    = (const float*)d_in[2];
    const float* Wv    = (const float*)d_in[3];
    const float* scale = (const float*)d_in[4];

    float* out0 = (float*)d_out;                 // [4,512,256]
    float* attn = out0 + 4 * 512 * 256;          // [4,512,512]

    float* eq    = (float*)d_ws;                 // [2048,256]
    float* ek    = eq + 2048 * 256;              // [2048,256]
    float* part0 = ek + 2048 * 256;              // [4,512,512] d-half 0
    float* part1 = part0 + 4 * 512 * 512;        // [4,512,512] d-half 1

    proj_kernel<<<512, 256, 0, stream>>>(query, value, Wq, Wv, eq, ek);
    scores_kernel<<<dim3(16, 16, 8), 256, 0, stream>>>(eq, ek, scale, part0, part1);
    softpv_kernel<<<dim3(64, 4), 512, 0, stream>>>(part0, part1, value, attn, out0);
}

// Round 10
// 69.763 us; speedup vs baseline: 1.0831x; 1.0831x over previous
//
#include <hip/hip_runtime.h>

#define LOG2E 1.4426950408889634f
#define TWO_LOG2E 2.885390081777927f

__device__ __forceinline__ float fast_exp2(float x) { return __builtin_amdgcn_exp2f(x); }
__device__ __forceinline__ float fast_rcp(float x)  { return __builtin_amdgcn_rcpf(x); }

// ---------------------------------------------------------------------------
// K1: projections + exp transform. Virtual M=4096 rows: blocks 0..255 ->
// exp2(2*log2e * query*Wq) -> eq, blocks 256..511 -> value*Wv -> ek.
// ---------------------------------------------------------------------------
__global__ __launch_bounds__(256) void proj_kernel(
    const float* __restrict__ query, const float* __restrict__ value,
    const float* __restrict__ Wq, const float* __restrict__ Wv,
    float* __restrict__ eq, float* __restrict__ ek)
{
    __shared__ float in_lds[8 * 256];
    const int t = threadIdx.x;
    const int row0 = blockIdx.x * 8;
    const float* src; const float* W; float* dst;
    if (row0 < 2048) { src = query + (size_t)row0 * 256; W = Wq; dst = eq + (size_t)row0 * 256; }
    else { const int r = row0 - 2048; src = value + (size_t)r * 256; W = Wv; dst = ek + (size_t)r * 256; }

    const float4* s4 = (const float4*)src;
    float4* l4 = (float4*)in_lds;
    l4[t] = s4[t];
    l4[t + 256] = s4[t + 256];
    __syncthreads();

    float acc[8];
#pragma unroll
    for (int r = 0; r < 8; ++r) acc[r] = 0.f;

    for (int d = 0; d < 256; d += 4) {
        const float w0 = W[(d + 0) * 256 + t];
        const float w1 = W[(d + 1) * 256 + t];
        const float w2 = W[(d + 2) * 256 + t];
        const float w3 = W[(d + 3) * 256 + t];
#pragma unroll
        for (int r = 0; r < 8; ++r) {
            const float4 v = *(const float4*)&in_lds[r * 256 + d];
            acc[r] = fmaf(v.x, w0, acc[r]);
            acc[r] = fmaf(v.y, w1, acc[r]);
            acc[r] = fmaf(v.z, w2, acc[r]);
            acc[r] = fmaf(v.w, w3, acc[r]);
        }
    }
#pragma unroll
    for (int r = 0; r < 8; ++r) dst[r * 256 + t] = fast_exp2(acc[r] * TWO_LOG2E);
}

// ---------------------------------------------------------------------------
// K2: raw shifted scores -> attn region (in place; K3 normalizes).
//   score*[q,k] = sum_d (-2*scale[d]) / (eq*ek + 1)  (constant shift vs true
//   score, softmax cancels). Paired-rcp: 1 rcp per 2 d-terms.
// 512 thr, 32(q) x 64(k) tile, full d=256 in two 128-chunks (no d-split, no
// part buffers). Per thread 2q x 2k (k rows tx, tx+32). Grid (8,16,4)=512
// blocks, ~50KB LDS -> 3 blocks/CU. k-row reads: bank (2*tx+d)%32 -> 2-way
// (free); q-row reads 2 addrs/wave -> broadcast.
// ---------------------------------------------------------------------------
#define SQ_ST 130
__global__ __launch_bounds__(512) void scores_kernel(
    const float* __restrict__ eq, const float* __restrict__ ek,
    const float* __restrict__ scale, float* __restrict__ sraw)
{
    __shared__ float q_lds[32 * SQ_ST];
    __shared__ float k_lds[64 * SQ_ST];
    __shared__ float sc_lds[256];

    const int t = threadIdx.x;
    const int tx = t & 31, ty = t >> 5;      // tx: k col (0..31), ty: q pair (0..15)
    const int ktg = blockIdx.x, qt = blockIdx.y, b = blockIdx.z;
    const float* qbase = eq + (size_t)(b * 512 + qt * 32) * 256;
    const float* kbase = ek + (size_t)(b * 512 + ktg * 64) * 256;

    if (t < 256) sc_lds[t] = -2.f * scale[t];

    float a00 = 0.f, a01 = 0.f, a10 = 0.f, a11 = 0.f;

    for (int dc = 0; dc < 256; dc += 128) {
        __syncthreads();
        // stage q: 32 rows x 128 floats = 1024 float4s
#pragma unroll
        for (int l = 0; l < 2; ++l) {
            const int idx = t + 512 * l;
            const int row = idx >> 5, c4 = (idx & 31) * 4;
            const float4 v = *(const float4*)&qbase[row * 256 + dc + c4];
            *(float2*)&q_lds[row * SQ_ST + c4]     = make_float2(v.x, v.y);
            *(float2*)&q_lds[row * SQ_ST + c4 + 2] = make_float2(v.z, v.w);
        }
        // stage k: 64 rows x 128 floats = 2048 float4s
#pragma unroll
        for (int l = 0; l < 4; ++l) {
            const int idx = t + 512 * l;
            const int row = idx >> 5, c4 = (idx & 31) * 4;
            const float4 v = *(const float4*)&kbase[row * 256 + dc + c4];
            *(float2*)&k_lds[row * SQ_ST + c4]     = make_float2(v.x, v.y);
            *(float2*)&k_lds[row * SQ_ST + c4 + 2] = make_float2(v.z, v.w);
        }
        __syncthreads();

#pragma unroll 4
        for (int d = 0; d < 128; d += 2) {
            const float2 s2 = *(const float2*)&sc_lds[dc + d];
            const float2 qa = *(const float2*)&q_lds[(ty * 2 + 0) * SQ_ST + d];
            const float2 qb = *(const float2*)&q_lds[(ty * 2 + 1) * SQ_ST + d];
            const float2 ka = *(const float2*)&k_lds[tx * SQ_ST + d];
            const float2 kb = *(const float2*)&k_lds[(tx + 32) * SQ_ST + d];

            {
                const float A = fmaf(qa.x, ka.x, 1.f), B = fmaf(qa.y, ka.y, 1.f);
                a00 = fmaf(fmaf(s2.y, A, s2.x * B), fast_rcp(A * B), a00);
            }
            {
                const float A = fmaf(qa.x, kb.x, 1.f), B = fmaf(qa.y, kb.y, 1.f);
                a01 = fmaf(fmaf(s2.y, A, s2.x * B), fast_rcp(A * B), a01);
            }
            {
                const float A = fmaf(qb.x, ka.x, 1.f), B = fmaf(qb.y, ka.y, 1.f);
                a10 = fmaf(fmaf(s2.y, A, s2.x * B), fast_rcp(A * B), a10);
            }
            {
                const float A = fmaf(qb.x, kb.x, 1.f), B = fmaf(qb.y, kb.y, 1.f);
                a11 = fmaf(fmaf(s2.y, A, s2.x * B), fast_rcp(A * B), a11);
            }
        }
    }

    const int qrow = b * 512 + qt * 32 + ty * 2;
    const int kcol = ktg * 64 + tx;
    sraw[(size_t)(qrow + 0) * 512 + kcol]      = a00;
    sraw[(size_t)(qrow + 0) * 512 + kcol + 32] = a01;
    sraw[(size_t)(qrow + 1) * 512 + kcol]      = a10;
    sraw[(size_t)(qrow + 1) * 512 + kcol + 32] = a11;
}

// ---------------------------------------------------------------------------
// K3: fused softmax + PV, issue-lean version.
// Block = (b, 8 q-rows), 512 thr (8 waves), grid (64,4) = 256 blocks.
// Softmax: wave w == row w; e[8] in registers (coalesced global reads of raw
//   scores), shfl_xor reduce; write normalized attn; raw exp -> s_lds.
// PV: wave w owns k in [64w, 64w+64); acc[8] float4 per lane (cols lane*4).
//   Per 4k: 4 coalesced 1KB global v loads (L2-resident) + 8 uniform
//   (broadcast) s_lds b128 reads + 128 fma -> fma-bound; value read once per
//   block. Cross-wave tree reduce in 32KB LDS (3 rounds).
// ---------------------------------------------------------------------------
#define SS_ROW 516
__global__ __launch_bounds__(512) void softpv_kernel(
    float* __restrict__ attn, const float* __restrict__ value,
    float* __restrict__ out)
{
    __shared__ float s_lds[8 * SS_ROW];      // raw exp, 16.5KB
    __shared__ float red[4 * 8 * 256];       // reduce buffer, 32KB
    __shared__ float inv_lds[8];

    const int t = threadIdx.x;
    const int w = t >> 6, lane = t & 63;
    const int qt = blockIdx.x, b = blockIdx.y;
    const int q0 = qt * 8;
    float* srow = attn + (size_t)(b * 512 + q0 + w) * 512;

    // ---- softmax (wave w = row w) ----
    float e[8];
    float m = -1e30f;
#pragma unroll
    for (int j = 0; j < 8; ++j) {
        e[j] = srow[lane + 64 * j];
        m = fmaxf(m, e[j]);
    }
#pragma unroll
    for (int off = 32; off; off >>= 1) m = fmaxf(m, __shfl_xor(m, off));

    float sum = 0.f;
#pragma unroll
    for (int j = 0; j < 8; ++j) {
        e[j] = fast_exp2((e[j] - m) * LOG2E);
        sum += e[j];
    }
#pragma unroll
    for (int off = 32; off; off >>= 1) sum += __shfl_xor(sum, off);

    const float inv = fast_rcp(sum);
#pragma unroll
    for (int j = 0; j < 8; ++j) {
        s_lds[w * SS_ROW + lane + 64 * j] = e[j];
        srow[lane + 64 * j] = e[j] * inv;
    }
    if (lane == 0) inv_lds[w] = inv;
    __syncthreads();

    // ---- PV: wave w covers k in [64w, 64w+64) ----
    float4 acc[8];
#pragma unroll
    for (int r = 0; r < 8; ++r) acc[r] = make_float4(0.f, 0.f, 0.f, 0.f);

    const float* vbase = value + (size_t)(b * 512 + 64 * w) * 256;
    for (int k4 = 0; k4 < 64; k4 += 4) {
        const float4 v0 = *(const float4*)&vbase[(k4 + 0) * 256 + lane * 4];
        const float4 v1 = *(const float4*)&vbase[(k4 + 1) * 256 + lane * 4];
        const float4 v2 = *(const float4*)&vbase[(k4 + 2) * 256 + lane * 4];
        const float4 v3 = *(const float4*)&vbase[(k4 + 3) * 256 + lane * 4];
#pragma unroll
        for (int r = 0; r < 8; ++r) {
            const float4 s4 = *(const float4*)&s_lds[r * SS_ROW + 64 * w + k4];
            acc[r].x = fmaf(s4.x, v0.x, acc[r].x); acc[r].y = fmaf(s4.x, v0.y, acc[r].y);
            acc[r].z = fmaf(s4.x, v0.z, acc[r].z); acc[r].w = fmaf(s4.x, v0.w, acc[r].w);
            acc[r].x = fmaf(s4.y, v1.x, acc[r].x); acc[r].y = fmaf(s4.y, v1.y, acc[r].y);
            acc[r].z = fmaf(s4.y, v1.z, acc[r].z); acc[r].w = fmaf(s4.y, v1.w, acc[r].w);
            acc[r].x = fmaf(s4.z, v2.x, acc[r].x); acc[r].y = fmaf(s4.z, v2.y, acc[r].y);
            acc[r].z = fmaf(s4.z, v2.z, acc[r].z); acc[r].w = fmaf(s4.z, v2.w, acc[r].w);
            acc[r].x = fmaf(s4.w, v3.x, acc[r].x); acc[r].y = fmaf(s4.w, v3.y, acc[r].y);
            acc[r].z = fmaf(s4.w, v3.z, acc[r].z); acc[r].w = fmaf(s4.w, v3.w, acc[r].w);
        }
    }

    // ---- cross-wave tree reduce (8 -> 4 -> 2 -> 1) ----
    if (w >= 4) {
#pragma unroll
        for (int r = 0; r < 8; ++r)
            *(float4*)&red[((w - 4) * 8 + r) * 256 + lane * 4] = acc[r];
    }
    __syncthreads();
    if (w < 4) {
#pragma unroll
        for (int r = 0; r < 8; ++r) {
            const float4 o = *(const float4*)&red[(w * 8 + r) * 256 + lane * 4];
            acc[r].x += o.x; acc[r].y += o.y; acc[r].z += o.z; acc[r].w += o.w;
        }
    }
    __syncthreads();
    if (w >= 2 && w < 4) {
#pragma unroll
        for (int r = 0; r < 8; ++r)
            *(float4*)&red[((w - 2) * 8 + r) * 256 + lane * 4] = acc[r];
    }
    __syncthreads();
    if (w < 2) {
#pragma unroll
        for (int r = 0; r < 8; ++r) {
            const float4 o = *(const float4*)&red[(w * 8 + r) * 256 + lane * 4];
            acc[r].x += o.x; acc[r].y += o.y; acc[r].z += o.z; acc[r].w += o.w;
        }
    }
    __syncthreads();
    if (w == 1) {
#pragma unroll
        for (int r = 0; r < 8; ++r)
            *(float4*)&red[r * 256 + lane * 4] = acc[r];
    }
    __syncthreads();
    if (w == 0) {
#pragma unroll
        for (int r = 0; r < 8; ++r) {
            const float4 o = *(const float4*)&red[r * 256 + lane * 4];
            const float iv = inv_lds[r];
            float4 res;
            res.x = (acc[r].x + o.x) * iv;
            res.y = (acc[r].y + o.y) * iv;
            res.z = (acc[r].z + o.z) * iv;
            res.w = (acc[r].w + o.w) * iv;
            *(float4*)&out[(size_t)(b * 512 + q0 + r) * 256 + lane * 4] = res;
        }
    }
}

extern "C" void kernel_launch(void* const* d_in, const int* in_sizes, int n_in,
                              void* d_out, int out_size, void* d_ws, size_t ws_size,
                              hipStream_t stream) {
    const float* query = (const float*)d_in[0];
    const float* value = (const float*)d_in[1];
    const float* Wq    = (const float*)d_in[2];
    const float* Wv    = (const float*)d_in[3];
    const float* scale = (const float*)d_in[4];

    float* out0 = (float*)d_out;                 // [4,512,256]
    float* attn = out0 + 4 * 512 * 256;          // [4,512,512] raw scores -> softmax in place

    float* eq = (float*)d_ws;                    // [2048,256]
    float* ek = eq + 2048 * 256;                 // [2048,256]

    proj_kernel<<<512, 256, 0, stream>>>(query, value, Wq, Wv, eq, ek);
    scores_kernel<<<dim3(8, 16, 4), 512, 0, stream>>>(eq, ek, scale, attn);
    softpv_kernel<<<dim3(64, 4), 512, 0, stream>>>(attn, value, out0);
}